// Round 5
// baseline (179.132 us; speedup 1.0000x reference)
//
#include <hip/hip_runtime.h>
#include <stdint.h>

// Problem constants (B=4096, D=1024 from setup_inputs)
#define BSZ 4096
#define DIM 1024
#define EPSV 1e-6f
#define MARGINV 0.3f
#define SROWS 4
#define PS_BLOCKS 2048                // parity-interleaved: even=sample, odd=prep
#define GL_BLOCKS 1024                // 32x32 tiles of the [B,B] loss matrix

// ---------------- Threefry-2x32 (bit-exact vs JAX lowering) ----------------
#define TF_ROT(x0, x1, r) { x0 += x1; x1 = ((x1 << r) | (x1 >> (32 - r))); x1 ^= x0; }

__host__ __device__ __forceinline__ void threefry2x32(uint32_t k0, uint32_t k1,
                                                      uint32_t c0, uint32_t c1,
                                                      uint32_t& o0, uint32_t& o1) {
  uint32_t ks2 = k0 ^ k1 ^ 0x1BD11BDAu;
  uint32_t x0 = c0 + k0;
  uint32_t x1 = c1 + k1;
  TF_ROT(x0, x1, 13) TF_ROT(x0, x1, 15) TF_ROT(x0, x1, 26) TF_ROT(x0, x1, 6)
  x0 += k1;  x1 += ks2 + 1u;
  TF_ROT(x0, x1, 17) TF_ROT(x0, x1, 29) TF_ROT(x0, x1, 16) TF_ROT(x0, x1, 24)
  x0 += ks2; x1 += k0 + 2u;
  TF_ROT(x0, x1, 13) TF_ROT(x0, x1, 15) TF_ROT(x0, x1, 26) TF_ROT(x0, x1, 6)
  x0 += k0;  x1 += k1 + 3u;
  TF_ROT(x0, x1, 17) TF_ROT(x0, x1, 29) TF_ROT(x0, x1, 16) TF_ROT(x0, x1, 24)
  x0 += k1;  x1 += ks2 + 4u;
  TF_ROT(x0, x1, 13) TF_ROT(x0, x1, 15) TF_ROT(x0, x1, 26) TF_ROT(x0, x1, 6)
  x0 += ks2; x1 += k0 + 5u;
  o0 = x0; o1 = x1;
}

// Two independent chains, statements interleaved for explicit ILP-2.
#define TFR2(r) { xa0 += xa1; xb0 += xb1; \
                  xa1 = ((xa1 << r) | (xa1 >> (32 - r))) ^ xa0; \
                  xb1 = ((xb1 << r) | (xb1 >> (32 - r))) ^ xb0; }

__device__ __forceinline__ void threefry_x2(uint32_t k0, uint32_t k1,
                                            uint32_t ca, uint32_t cb,
                                            uint32_t& oa, uint32_t& ob) {
  const uint32_t ks2 = k0 ^ k1 ^ 0x1BD11BDAu;
  uint32_t xa0 = k0, xa1 = ca + k1;
  uint32_t xb0 = k0, xb1 = cb + k1;
  TFR2(13) TFR2(15) TFR2(26) TFR2(6)
  xa0 += k1;  xa1 += ks2 + 1u;  xb0 += k1;  xb1 += ks2 + 1u;
  TFR2(17) TFR2(29) TFR2(16) TFR2(24)
  xa0 += ks2; xa1 += k0 + 2u;   xb0 += ks2; xb1 += k0 + 2u;
  TFR2(13) TFR2(15) TFR2(26) TFR2(6)
  xa0 += k0;  xa1 += k1 + 3u;   xb0 += k0;  xb1 += k1 + 3u;
  TFR2(17) TFR2(29) TFR2(16) TFR2(24)
  xa0 += k1;  xa1 += ks2 + 4u;  xb0 += k1;  xb1 += ks2 + 4u;
  TFR2(13) TFR2(15) TFR2(26) TFR2(6)
  xa0 += ks2; xa1 += k0 + 5u;   xb0 += ks2; xb1 += k0 + 5u;
  oa = xa0 ^ xa1;
  ob = xb0 ^ xb1;
}

// ---------------- Kernel 1: FUSED sample (VALU-bound) + prep (memory-bound) ----
// R5: match-MASK rewrite. R4 showed VGPR_Count=32 with lj[16] nominally live
// across the whole hot loop -> compiler dropped lj residency (reload stalls,
// VALUBusy 41%). Now lj lives only long enough to build a 16-bit match mask per
// row (mrow[4], 4 regs); hot-loop live set ~15 VGPRs -> no reloads at any cap.
__global__ __launch_bounds__(256, 8) void prep_sample_kernel(
    const float* __restrict__ F, uint8_t* __restrict__ Fq,
    float* __restrict__ norm2, float* __restrict__ sums, float* __restrict__ nv,
    const int* __restrict__ labels, int* __restrict__ pos_idx, int* __restrict__ neg_idx,
    uint32_t p0, uint32_t p1, uint32_t n0, uint32_t n1) {
  __shared__ int plist[SROWS * 64];
  __shared__ int pcnt[SROWS];
  __shared__ unsigned long long swp[SROWS];
  __shared__ unsigned long long swn[SROWS];
  const int t = threadIdx.x;

  if (blockIdx.x & 1) {
    // ================= PREP branch: one wave per row =================
    const int w = t >> 6, l = t & 63;
    const int r = (blockIdx.x >> 1) * 4 + w;
    const float4* src = (const float4*)(F + (size_t)r * DIM);
    uint32_t* dst = (uint32_t*)(Fq + (size_t)r * DIM);
    float s = 0.f, q = 0.f;
#pragma unroll
    for (int c = 0; c < 4; ++c) {
      float4 v = src[c * 64 + l];
      s += (v.x + v.y) + (v.z + v.w);
      q += v.x * v.x + v.y * v.y + v.z * v.z + v.w * v.w;
      int wd = 0;
      wd = __builtin_amdgcn_cvt_pk_fp8_f32(v.x, v.y, wd, false);  // bytes 0,1
      wd = __builtin_amdgcn_cvt_pk_fp8_f32(v.z, v.w, wd, true);   // bytes 2,3
      dst[c * 64 + l] = (uint32_t)wd;
    }
    for (int off = 32; off; off >>= 1) { s += __shfl_xor(s, off); q += __shfl_xor(q, off); }
    if (l == 0) {
      norm2[r] = q; sums[r] = s;
      nv[r] = q + 2.0f * EPSV * s;
    }
    return;
  }

  // ================= SAMPLE branch: 4 rows/block =================
  const int i0 = (blockIdx.x >> 1) * SROWS;
  if (t < SROWS) { pcnt[t] = 0; swp[t] = 0ull; swn[t] = 0ull; }
  uint32_t mrow[SROWS];
  {
    int lj[16];
#pragma unroll
    for (int c = 0; c < 16; ++c) lj[c] = labels[c * 256 + t];
#pragma unroll
    for (int r = 0; r < SROWS; ++r) {
      const int li = labels[i0 + r];  // block-uniform -> scalar load
      uint32_t m = 0u;
#pragma unroll
      for (int c = 0; c < 16; ++c) m |= (lj[c] == li) ? (1u << c) : 0u;
      mrow[r] = m;
    }
  }  // lj dead here — hot loop below only needs mrow[4]
  __syncthreads();
  const int lane = t & 63;
#pragma unroll 1  // keep body compact (8 inlined threefry_x2 chains) — I$ is 32 KB
  for (int r = 0; r < SROWS; ++r) {
    const uint32_t mr = mrow[r];
    const uint32_t base = (uint32_t)(i0 + r) * (uint32_t)BSZ + (uint32_t)t;
    uint32_t bestn = 0u;
    // Branch-free hot loop; candidate push deferred to mask re-scan below.
#pragma unroll
    for (int c = 0; c < 16; c += 2) {
      uint32_t bitsA, bitsB;
      threefry_x2(n0, n1, base + (uint32_t)(c * 256), base + (uint32_t)((c + 1) * 256),
                  bitsA, bitsB);
      const uint32_t packA = ((bitsA >> 5) & 0xFFFFFFF0u) | (uint32_t)(15 - c);
      const uint32_t packB = ((bitsB >> 5) & 0xFFFFFFF0u) | (uint32_t)(14 - c);
      const uint32_t vA = (mr & (1u << c)) ? 0u : packA;
      const uint32_t vB = (mr & (2u << c)) ? 0u : packB;
      const uint32_t mab = vA > vB ? vA : vB;  // low-4-bit tags differ: no cross-c tie
      bestn = bestn > mab ? bestn : mab;
    }
    // lane-local 32-bit -> global 64-bit key (tie -> lower j, matching JAX argmax)
    unsigned long long keyn = 0ull;
    if (bestn) {
      const int c = 15 - (int)(bestn & 15u);
      const int j = c * 256 + t;
      keyn = ((unsigned long long)(bestn >> 4) << 32) | (uint32_t)(~j);
    }
    for (int off = 32; off; off >>= 1) {
      unsigned long long o = __shfl_xor(keyn, off);
      if (o > keyn) keyn = o;
    }
    if (lane == 0) atomicMax(&swn[r], keyn);
    // Candidate push (mask re-scan): rare divergence outside the hot loop
#pragma unroll
    for (int c = 0; c < 16; ++c) {
      if (mr & (1u << c)) {
        int sl = atomicAdd(&pcnt[r], 1);
        if (sl < 64) plist[r * 64 + sl] = c * 256 + t;
      }
    }
  }
  __syncthreads();  // fences plist/pcnt/swn
  // POS phase: wave w handles row w's candidate list (~8 entries)
  const int w = t >> 6;
  {
    const int cnt = pcnt[w] < 64 ? pcnt[w] : 64;
    if (lane < cnt) {
      const int j = plist[w * 64 + lane];
      uint32_t y0, y1;
      threefry2x32(p0, p1, 0u, (uint32_t)(i0 + w) * (uint32_t)BSZ + (uint32_t)j, y0, y1);
      const unsigned long long key =
          ((unsigned long long)((y0 ^ y1) >> 9) << 32) | (uint32_t)(~j);
      atomicMax(&swp[w], key);
    }
  }
  __syncthreads();
  if (t < SROWS) {
    pos_idx[i0 + t] = (int)(~(uint32_t)swp[t]);  // i itself always matches -> swp != 0
    const unsigned long long vn = swn[t];
    neg_idx[i0 + t] = (vn == 0ull) ? 0 : (int)(~(uint32_t)vn);
  }
}

// ---------------- Kernel 2: FUSED gemm+loss — G is never materialized --------
// R5: per 128x128 tile (bi,bj): S_P = P·F^T and S_N = N·F^T via gathered fp8
// A-panels (per-lane global_load_lds source = row pos_idx/neg_idx), then the
// triplet loss applied in the epilogue from the f32 accumulators and reduced to
// one partial per block. Deletes the 32 MB Gb write + mirror store + the whole
// 26-us random-gather loss kernel. Fq (4 MB) is L2-resident -> near-zero HBM.
using int8v = __attribute__((ext_vector_type(8))) int;
using int4v = __attribute__((ext_vector_type(4))) int;
using f32x4 = __attribute__((ext_vector_type(4))) float;

__device__ __forceinline__ void async_load16(const void* g, void* l) {
  __builtin_amdgcn_global_load_lds((__attribute__((address_space(1))) void*)g,
                                   (__attribute__((address_space(3))) void*)l, 16, 0, 0);
}

__global__ __launch_bounds__(256, 2) void gemmloss_kernel(
    const uint8_t* __restrict__ Fq, const float* __restrict__ norm2,
    const float* __restrict__ sums, const float* __restrict__ nv,
    const int* __restrict__ pos_idx, const int* __restrict__ neg_idx,
    float* __restrict__ partial) {
  __shared__ __align__(16) uint8_t lAP[128 * 128];
  __shared__ __align__(16) uint8_t lAN[128 * 128];
  __shared__ __align__(16) uint8_t lB[128 * 128];
  __shared__ float ca_l[128], cb_l[128];
  __shared__ float ps[4];
  const int t = threadIdx.x;
  const int bi = blockIdx.x >> 5;   // row tile (anchors i)
  const int bj = blockIdx.x & 31;   // col tile (gallery j)

  // Per-row loss constants (depend on pos/neg gather) -> LDS once
  if (t < 128) {
    const float deps2 = (float)DIM * EPSV * EPSV;
    const int a = pos_idx[bi * 128 + t], b = neg_idx[bi * 128 + t];
    ca_l[t] = norm2[a] - 2.0f * EPSV * sums[a] + deps2;
    cb_l[t] = norm2[b] - 2.0f * EPSV * sums[b] + deps2;
  }

  const int l = t & 63;
  const int w = t >> 6;
  const int wm = (w >> 1) * 64;
  const int wn = (w & 1) * 64;

  f32x4 accP[4][4] = {}, accN[4][4] = {};

  const int srow = t >> 3;  // 0..31
  const int scol = (((t & 7) ^ ((t >> 3) & 7)) << 4);  // XOR-swizzled source chunk
  // Gathered row byte-offsets (iteration-invariant), kept as 32-bit (Fq = 4 MB)
  uint32_t roP[4], roN[4], roB[4];
#pragma unroll
  for (int ld = 0; ld < 4; ++ld) {
    const int rr = srow + ld * 32;
    roP[ld] = (uint32_t)pos_idx[bi * 128 + rr] * (uint32_t)DIM + (uint32_t)scol;
    roN[ld] = (uint32_t)neg_idx[bi * 128 + rr] * (uint32_t)DIM + (uint32_t)scol;
    roB[ld] = (uint32_t)(bj * 128 + rr) * (uint32_t)DIM + (uint32_t)scol;
  }

  // Fragment LDS byte offsets (iteration-invariant): row fra, chunks c0, c0+1
  const int fr = l & 15;
  const int c0 = (l >> 4) * 2;
  int offA[4][2], offB[4][2];
#pragma unroll
  for (int tm = 0; tm < 4; ++tm) {
    const int fra = wm + tm * 16 + fr, sw = fra & 7;
    offA[tm][0] = fra * 128 + ((c0 ^ sw) << 4);
    offA[tm][1] = fra * 128 + (((c0 + 1) ^ sw) << 4);
    const int frb = wn + tm * 16 + fr, sb = frb & 7;
    offB[tm][0] = frb * 128 + ((c0 ^ sb) << 4);
    offB[tm][1] = frb * 128 + (((c0 + 1) ^ sb) << 4);
  }

  for (int it = 0; it < 8; ++it) {  // K = 1024, BK = 128
    const uint32_t k0 = (uint32_t)(it * 128);
    __syncthreads();
#pragma unroll
    for (int ld = 0; ld < 4; ++ld) {
      async_load16(Fq + roP[ld] + k0, (char*)lAP + (ld * 256 + t) * 16);
      async_load16(Fq + roN[ld] + k0, (char*)lAN + (ld * 256 + t) * 16);
      async_load16(Fq + roB[ld] + k0, (char*)lB + (ld * 256 + t) * 16);
    }
    __syncthreads();
    int8v bv[4];
#pragma unroll
    for (int tn = 0; tn < 4; ++tn) {
      int4v blo = *(const int4v*)&lB[offB[tn][0]];
      int4v bhi = *(const int4v*)&lB[offB[tn][1]];
      bv[tn] = __builtin_shufflevector(blo, bhi, 0, 1, 2, 3, 4, 5, 6, 7);
    }
#pragma unroll
    for (int tm = 0; tm < 4; ++tm) {
      int4v plo = *(const int4v*)&lAP[offA[tm][0]];
      int4v phi = *(const int4v*)&lAP[offA[tm][1]];
      int8v avP = __builtin_shufflevector(plo, phi, 0, 1, 2, 3, 4, 5, 6, 7);
      int4v nlo = *(const int4v*)&lAN[offA[tm][0]];
      int4v nhi = *(const int4v*)&lAN[offA[tm][1]];
      int8v avN = __builtin_shufflevector(nlo, nhi, 0, 1, 2, 3, 4, 5, 6, 7);
#pragma unroll
      for (int tn = 0; tn < 4; ++tn) {
        accP[tm][tn] = __builtin_amdgcn_mfma_scale_f32_16x16x128_f8f6f4(
            avP, bv[tn], accP[tm][tn], 0, 0, 0, 0x7F7F7F7F, 0, 0x7F7F7F7F);
        accN[tm][tn] = __builtin_amdgcn_mfma_scale_f32_16x16x128_f8f6f4(
            avN, bv[tn], accN[tm][tn], 0, 0, 0, 0x7F7F7F7F, 0, 0x7F7F7F7F);
      }
    }
  }

  // Epilogue: loss from f32 accumulators. C/D: col = lane&15, row = (lane>>4)*4+reg
  const int cr = (l >> 4) * 4;
  const int cc = l & 15;
  float nvj[4];
#pragma unroll
  for (int tn = 0; tn < 4; ++tn) nvj[tn] = nv[bj * 128 + wn + tn * 16 + cc];
  float s = 0.f;
#pragma unroll
  for (int tm = 0; tm < 4; ++tm) {
#pragma unroll
    for (int e = 0; e < 4; ++e) {
      const int il = wm + tm * 16 + cr + e;
      const float cai = ca_l[il], cbi = cb_l[il];
#pragma unroll
      for (int tn = 0; tn < 4; ++tn) {
        const float dap = sqrtf(fmaxf(fmaf(-2.f, accP[tm][tn][e], nvj[tn] + cai), 1e-12f));
        const float dan = sqrtf(fmaxf(fmaf(-2.f, accN[tm][tn][e], nvj[tn] + cbi), 1e-12f));
        s += fmaxf(dap - dan + MARGINV, 0.f);
      }
    }
  }
  for (int off = 32; off; off >>= 1) s += __shfl_xor(s, off);
  const int lane = t & 63;
  if (lane == 0) ps[w] = s;
  __syncthreads();
  if (t == 0) partial[blockIdx.x] = (ps[0] + ps[1]) + (ps[2] + ps[3]);
}

// ---------------- Kernel 3: finalize (1 block, 1024 partials) ----------------
__global__ __launch_bounds__(256) void finalize_kernel(const float* __restrict__ partial,
                                                       float* __restrict__ out) {
  const int t = threadIdx.x;
  const float4* P4 = (const float4*)partial;  // 1024 floats = 256 float4
  float4 v = P4[t];
  float s = (v.x + v.y) + (v.z + v.w);
  for (int off = 32; off; off >>= 1) s += __shfl_xor(s, off);
  __shared__ float ps[4];
  const int w = t >> 6, lane = t & 63;
  if (lane == 0) ps[w] = s;
  __syncthreads();
  if (t == 0)
    out[0] = ((ps[0] + ps[1]) + (ps[2] + ps[3])) * (1.0f / ((float)BSZ * (float)BSZ));
}

// ---------------- Launch ----------------
extern "C" void kernel_launch(void* const* d_in, const int* in_sizes, int n_in,
                              void* d_out, int out_size, void* d_ws, size_t ws_size,
                              hipStream_t stream) {
  const float* feat = (const float*)d_in[0];
  const int* labels = (const int*)d_in[1];
  float* out = (float*)d_out;

  char* ws = (char*)d_ws;
  uint8_t* Fq      = (uint8_t*)ws;                                // 4 MB
  float* norm2     = (float*)(ws + (size_t)4194304);              // 16 KB
  float* sums      = (float*)(ws + (size_t)4194304 + 16384);      // 16 KB
  float* nv        = (float*)(ws + (size_t)4194304 + 32768);      // 16 KB
  int* pos_idx     = (int*)  (ws + (size_t)4194304 + 49152);      // 16 KB
  int* neg_idx     = (int*)  (ws + (size_t)4194304 + 65536);      // 16 KB
  float* partial   = (float*)(ws + (size_t)4194304 + 81920);      // 4 KB

  // JAX partitionable split: k_i = threefry(base_key=(0,42), (0, i))
  uint32_t k1a, k1b, k2a, k2b;
  threefry2x32(0u, 42u, 0u, 0u, k1a, k1b);  // k1 -> pos uniforms
  threefry2x32(0u, 42u, 0u, 1u, k2a, k2b);  // k2 -> neg uniforms

  prep_sample_kernel<<<dim3(PS_BLOCKS), dim3(256), 0, stream>>>(
      feat, Fq, norm2, sums, nv, labels, pos_idx, neg_idx, k1a, k1b, k2a, k2b);
  gemmloss_kernel<<<dim3(GL_BLOCKS), dim3(256), 0, stream>>>(
      Fq, norm2, sums, nv, pos_idx, neg_idx, partial);
  finalize_kernel<<<dim3(1), dim3(256), 0, stream>>>(partial, out);
}

// Round 6
// 144.906 us; speedup vs baseline: 1.2362x; 1.2362x over previous
//
#include <hip/hip_runtime.h>
#include <stdint.h>

// Problem constants (B=4096, D=1024 from setup_inputs)
#define BSZ 4096
#define DIM 1024
#define EPSV 1e-6f
#define MARGINV 0.3f
#define SROWS 4
#define SAMPLE_BLOCKS 1024            // blocks [0,1024): sample (contiguous -> all 8 XCDs)
#define PS_BLOCKS 2048                // blocks [1024,2048): prep
#define GL_BLOCKS 1024                // 32x32 tiles of the [B,B] loss matrix

// R6: rotate helper. Device: single v_alignbit_b32 (rotl(x,r) == alignbit(x,x,32-r));
// host: portable shifts. Bit-identical. (R5 counters: VALU issue ~31 us matches the
// 3-op rotate model, not the 1-op alignbit model -> compiler wasn't fusing it.)
__host__ __device__ __forceinline__ uint32_t rotl32(uint32_t x, uint32_t r) {
#ifdef __HIP_DEVICE_COMPILE__
  return __builtin_amdgcn_alignbit(x, x, 32u - r);
#else
  return (x << r) | (x >> (32u - r));
#endif
}

// ---------------- Threefry-2x32 (bit-exact vs JAX lowering) ----------------
#define TF_ROT(x0, x1, r) { x0 += x1; x1 = rotl32(x1, r) ^ x0; }

__host__ __device__ __forceinline__ void threefry2x32(uint32_t k0, uint32_t k1,
                                                      uint32_t c0, uint32_t c1,
                                                      uint32_t& o0, uint32_t& o1) {
  uint32_t ks2 = k0 ^ k1 ^ 0x1BD11BDAu;
  uint32_t x0 = c0 + k0;
  uint32_t x1 = c1 + k1;
  TF_ROT(x0, x1, 13) TF_ROT(x0, x1, 15) TF_ROT(x0, x1, 26) TF_ROT(x0, x1, 6)
  x0 += k1;  x1 += ks2 + 1u;
  TF_ROT(x0, x1, 17) TF_ROT(x0, x1, 29) TF_ROT(x0, x1, 16) TF_ROT(x0, x1, 24)
  x0 += ks2; x1 += k0 + 2u;
  TF_ROT(x0, x1, 13) TF_ROT(x0, x1, 15) TF_ROT(x0, x1, 26) TF_ROT(x0, x1, 6)
  x0 += k0;  x1 += k1 + 3u;
  TF_ROT(x0, x1, 17) TF_ROT(x0, x1, 29) TF_ROT(x0, x1, 16) TF_ROT(x0, x1, 24)
  x0 += k1;  x1 += ks2 + 4u;
  TF_ROT(x0, x1, 13) TF_ROT(x0, x1, 15) TF_ROT(x0, x1, 26) TF_ROT(x0, x1, 6)
  x0 += ks2; x1 += k0 + 5u;
  o0 = x0; o1 = x1;
}

// Two independent chains, statements interleaved for explicit ILP-2.
#define TFR2(r) { xa0 += xa1; xb0 += xb1; \
                  xa1 = rotl32(xa1, r) ^ xa0; \
                  xb1 = rotl32(xb1, r) ^ xb0; }

__device__ __forceinline__ void threefry_x2(uint32_t k0, uint32_t k1,
                                            uint32_t ca, uint32_t cb,
                                            uint32_t& oa, uint32_t& ob) {
  const uint32_t ks2 = k0 ^ k1 ^ 0x1BD11BDAu;
  uint32_t xa0 = k0, xa1 = ca + k1;
  uint32_t xb0 = k0, xb1 = cb + k1;
  TFR2(13) TFR2(15) TFR2(26) TFR2(6)
  xa0 += k1;  xa1 += ks2 + 1u;  xb0 += k1;  xb1 += ks2 + 1u;
  TFR2(17) TFR2(29) TFR2(16) TFR2(24)
  xa0 += ks2; xa1 += k0 + 2u;   xb0 += ks2; xb1 += k0 + 2u;
  TFR2(13) TFR2(15) TFR2(26) TFR2(6)
  xa0 += k0;  xa1 += k1 + 3u;   xb0 += k0;  xb1 += k1 + 3u;
  TFR2(17) TFR2(29) TFR2(16) TFR2(24)
  xa0 += k1;  xa1 += ks2 + 4u;  xb0 += k1;  xb1 += ks2 + 4u;
  TFR2(13) TFR2(15) TFR2(26) TFR2(6)
  xa0 += ks2; xa1 += k0 + 5u;   xb0 += ks2; xb1 += k0 + 5u;
  oa = xa0 ^ xa1;
  ob = xb0 ^ xb1;
}

// ---------------- Kernel 1: FUSED sample (VALU-bound) + prep (memory-bound) ----
// R6: CONTIGUOUS split. R4/R5's parity interleave (even=sample, odd=prep)
// aliased with the bid%8 XCD round-robin: ALL sample blocks landed on XCDs
// {0,2,4,6} -> half the chip ran the 31-us VALU workload (62 us wall), half
// idled after prep. Chip-avg VALUBusy (85+4)/2 ~= 45% — matched R5's counters.
// Contiguous halves round-robin both classes over all 8 XCDs.
__global__ __launch_bounds__(256, 8) void prep_sample_kernel(
    const float* __restrict__ F, uint8_t* __restrict__ Fq,
    float* __restrict__ norm2, float* __restrict__ sums, float* __restrict__ nv,
    const int* __restrict__ labels, int* __restrict__ pos_idx, int* __restrict__ neg_idx,
    uint32_t p0, uint32_t p1, uint32_t n0, uint32_t n1) {
  __shared__ int plist[SROWS * 64];
  __shared__ int pcnt[SROWS];
  __shared__ unsigned long long swp[SROWS];
  __shared__ unsigned long long swn[SROWS];
  const int t = threadIdx.x;

  if (blockIdx.x >= SAMPLE_BLOCKS) {
    // ================= PREP branch: one wave per row =================
    const int w = t >> 6, l = t & 63;
    const int r = (blockIdx.x - SAMPLE_BLOCKS) * 4 + w;
    const float4* src = (const float4*)(F + (size_t)r * DIM);
    uint32_t* dst = (uint32_t*)(Fq + (size_t)r * DIM);
    float s = 0.f, q = 0.f;
#pragma unroll
    for (int c = 0; c < 4; ++c) {
      float4 v = src[c * 64 + l];
      s += (v.x + v.y) + (v.z + v.w);
      q += v.x * v.x + v.y * v.y + v.z * v.z + v.w * v.w;
      int wd = 0;
      wd = __builtin_amdgcn_cvt_pk_fp8_f32(v.x, v.y, wd, false);  // bytes 0,1
      wd = __builtin_amdgcn_cvt_pk_fp8_f32(v.z, v.w, wd, true);   // bytes 2,3
      dst[c * 64 + l] = (uint32_t)wd;
    }
    for (int off = 32; off; off >>= 1) { s += __shfl_xor(s, off); q += __shfl_xor(q, off); }
    if (l == 0) {
      norm2[r] = q; sums[r] = s;
      nv[r] = q + 2.0f * EPSV * s;
    }
    return;
  }

  // ================= SAMPLE branch: 4 rows/block =================
  const int i0 = blockIdx.x * SROWS;
  if (t < SROWS) { pcnt[t] = 0; swp[t] = 0ull; swn[t] = 0ull; }
  uint32_t mrow[SROWS];
  {
    int lj[16];
#pragma unroll
    for (int c = 0; c < 16; ++c) lj[c] = labels[c * 256 + t];
#pragma unroll
    for (int r = 0; r < SROWS; ++r) {
      const int li = labels[i0 + r];  // block-uniform -> scalar load
      uint32_t m = 0u;
#pragma unroll
      for (int c = 0; c < 16; ++c) m |= (lj[c] == li) ? (1u << c) : 0u;
      mrow[r] = m;
    }
  }  // lj dead here — hot loop below only needs mrow[4]
  __syncthreads();
  const int lane = t & 63;
#pragma unroll 1  // keep body compact (8 inlined threefry_x2 chains) — I$ is 32 KB
  for (int r = 0; r < SROWS; ++r) {
    const uint32_t mr = mrow[r];
    const uint32_t base = (uint32_t)(i0 + r) * (uint32_t)BSZ + (uint32_t)t;
    uint32_t bestn = 0u;
    // Branch-free hot loop; candidate push deferred to mask re-scan below.
#pragma unroll
    for (int c = 0; c < 16; c += 2) {
      uint32_t bitsA, bitsB;
      threefry_x2(n0, n1, base + (uint32_t)(c * 256), base + (uint32_t)((c + 1) * 256),
                  bitsA, bitsB);
      const uint32_t packA = ((bitsA >> 5) & 0xFFFFFFF0u) | (uint32_t)(15 - c);
      const uint32_t packB = ((bitsB >> 5) & 0xFFFFFFF0u) | (uint32_t)(14 - c);
      const uint32_t vA = (mr & (1u << c)) ? 0u : packA;
      const uint32_t vB = (mr & (2u << c)) ? 0u : packB;
      const uint32_t mab = vA > vB ? vA : vB;  // low-4-bit tags differ: no cross-c tie
      bestn = bestn > mab ? bestn : mab;
    }
    // lane-local 32-bit -> global 64-bit key (tie -> lower j, matching JAX argmax)
    unsigned long long keyn = 0ull;
    if (bestn) {
      const int c = 15 - (int)(bestn & 15u);
      const int j = c * 256 + t;
      keyn = ((unsigned long long)(bestn >> 4) << 32) | (uint32_t)(~j);
    }
    for (int off = 32; off; off >>= 1) {
      unsigned long long o = __shfl_xor(keyn, off);
      if (o > keyn) keyn = o;
    }
    if (lane == 0) atomicMax(&swn[r], keyn);
    // Candidate push (mask re-scan): rare divergence outside the hot loop
#pragma unroll
    for (int c = 0; c < 16; ++c) {
      if (mr & (1u << c)) {
        int sl = atomicAdd(&pcnt[r], 1);
        if (sl < 64) plist[r * 64 + sl] = c * 256 + t;
      }
    }
  }
  __syncthreads();  // fences plist/pcnt/swn
  // POS phase: wave w handles row w's candidate list (~8 entries)
  const int w = t >> 6;
  {
    const int cnt = pcnt[w] < 64 ? pcnt[w] : 64;
    if (lane < cnt) {
      const int j = plist[w * 64 + lane];
      uint32_t y0, y1;
      threefry2x32(p0, p1, 0u, (uint32_t)(i0 + w) * (uint32_t)BSZ + (uint32_t)j, y0, y1);
      const unsigned long long key =
          ((unsigned long long)((y0 ^ y1) >> 9) << 32) | (uint32_t)(~j);
      atomicMax(&swp[w], key);
    }
  }
  __syncthreads();
  if (t < SROWS) {
    pos_idx[i0 + t] = (int)(~(uint32_t)swp[t]);  // i itself always matches -> swp != 0
    const unsigned long long vn = swn[t];
    neg_idx[i0 + t] = (vn == 0ull) ? 0 : (int)(~(uint32_t)vn);
  }
}

// ---------------- Kernel 2: FUSED gemm+loss — G is never materialized --------
// Per 128x128 tile (bi,bj): S_P = P·F^T and S_N = N·F^T via gathered fp8
// A-panels (per-lane global_load_lds source = row pos_idx/neg_idx), then the
// triplet loss applied in the epilogue from the f32 accumulators and reduced to
// one partial per block. No 32 MB G write, no random-gather loss kernel.
using int8v = __attribute__((ext_vector_type(8))) int;
using int4v = __attribute__((ext_vector_type(4))) int;
using f32x4 = __attribute__((ext_vector_type(4))) float;

__device__ __forceinline__ void async_load16(const void* g, void* l) {
  __builtin_amdgcn_global_load_lds((__attribute__((address_space(1))) void*)g,
                                   (__attribute__((address_space(3))) void*)l, 16, 0, 0);
}

__global__ __launch_bounds__(256, 2) void gemmloss_kernel(
    const uint8_t* __restrict__ Fq, const float* __restrict__ norm2,
    const float* __restrict__ sums, const float* __restrict__ nv,
    const int* __restrict__ pos_idx, const int* __restrict__ neg_idx,
    float* __restrict__ partial) {
  __shared__ __align__(16) uint8_t lAP[128 * 128];
  __shared__ __align__(16) uint8_t lAN[128 * 128];
  __shared__ __align__(16) uint8_t lB[128 * 128];
  __shared__ float ca_l[128], cb_l[128];
  __shared__ float ps[4];
  const int t = threadIdx.x;
  const int bi = blockIdx.x >> 5;   // row tile (anchors i)
  const int bj = blockIdx.x & 31;   // col tile (gallery j)

  // Per-row loss constants (depend on pos/neg gather) -> LDS once
  if (t < 128) {
    const float deps2 = (float)DIM * EPSV * EPSV;
    const int a = pos_idx[bi * 128 + t], b = neg_idx[bi * 128 + t];
    ca_l[t] = norm2[a] - 2.0f * EPSV * sums[a] + deps2;
    cb_l[t] = norm2[b] - 2.0f * EPSV * sums[b] + deps2;
  }

  const int l = t & 63;
  const int w = t >> 6;
  const int wm = (w >> 1) * 64;
  const int wn = (w & 1) * 64;

  f32x4 accP[4][4] = {}, accN[4][4] = {};

  const int srow = t >> 3;  // 0..31
  const int scol = (((t & 7) ^ ((t >> 3) & 7)) << 4);  // XOR-swizzled source chunk
  // Gathered row byte-offsets (iteration-invariant), kept as 32-bit (Fq = 4 MB)
  uint32_t roP[4], roN[4], roB[4];
#pragma unroll
  for (int ld = 0; ld < 4; ++ld) {
    const int rr = srow + ld * 32;
    roP[ld] = (uint32_t)pos_idx[bi * 128 + rr] * (uint32_t)DIM + (uint32_t)scol;
    roN[ld] = (uint32_t)neg_idx[bi * 128 + rr] * (uint32_t)DIM + (uint32_t)scol;
    roB[ld] = (uint32_t)(bj * 128 + rr) * (uint32_t)DIM + (uint32_t)scol;
  }

  // Fragment LDS byte offsets (iteration-invariant): row fra, chunks c0, c0+1
  const int fr = l & 15;
  const int c0 = (l >> 4) * 2;
  int offA[4][2], offB[4][2];
#pragma unroll
  for (int tm = 0; tm < 4; ++tm) {
    const int fra = wm + tm * 16 + fr, sw = fra & 7;
    offA[tm][0] = fra * 128 + ((c0 ^ sw) << 4);
    offA[tm][1] = fra * 128 + (((c0 + 1) ^ sw) << 4);
    const int frb = wn + tm * 16 + fr, sb = frb & 7;
    offB[tm][0] = frb * 128 + ((c0 ^ sb) << 4);
    offB[tm][1] = frb * 128 + (((c0 + 1) ^ sb) << 4);
  }

  for (int it = 0; it < 8; ++it) {  // K = 1024, BK = 128
    const uint32_t k0 = (uint32_t)(it * 128);
    __syncthreads();
#pragma unroll
    for (int ld = 0; ld < 4; ++ld) {
      async_load16(Fq + roP[ld] + k0, (char*)lAP + (ld * 256 + t) * 16);
      async_load16(Fq + roN[ld] + k0, (char*)lAN + (ld * 256 + t) * 16);
      async_load16(Fq + roB[ld] + k0, (char*)lB + (ld * 256 + t) * 16);
    }
    __syncthreads();
    int8v bv[4];
#pragma unroll
    for (int tn = 0; tn < 4; ++tn) {
      int4v blo = *(const int4v*)&lB[offB[tn][0]];
      int4v bhi = *(const int4v*)&lB[offB[tn][1]];
      bv[tn] = __builtin_shufflevector(blo, bhi, 0, 1, 2, 3, 4, 5, 6, 7);
    }
#pragma unroll
    for (int tm = 0; tm < 4; ++tm) {
      int4v plo = *(const int4v*)&lAP[offA[tm][0]];
      int4v phi = *(const int4v*)&lAP[offA[tm][1]];
      int8v avP = __builtin_shufflevector(plo, phi, 0, 1, 2, 3, 4, 5, 6, 7);
      int4v nlo = *(const int4v*)&lAN[offA[tm][0]];
      int4v nhi = *(const int4v*)&lAN[offA[tm][1]];
      int8v avN = __builtin_shufflevector(nlo, nhi, 0, 1, 2, 3, 4, 5, 6, 7);
#pragma unroll
      for (int tn = 0; tn < 4; ++tn) {
        accP[tm][tn] = __builtin_amdgcn_mfma_scale_f32_16x16x128_f8f6f4(
            avP, bv[tn], accP[tm][tn], 0, 0, 0, 0x7F7F7F7F, 0, 0x7F7F7F7F);
        accN[tm][tn] = __builtin_amdgcn_mfma_scale_f32_16x16x128_f8f6f4(
            avN, bv[tn], accN[tm][tn], 0, 0, 0, 0x7F7F7F7F, 0, 0x7F7F7F7F);
      }
    }
  }

  // Epilogue: loss from f32 accumulators. C/D: col = lane&15, row = (lane>>4)*4+reg
  const int cr = (l >> 4) * 4;
  const int cc = l & 15;
  float nvj[4];
#pragma unroll
  for (int tn = 0; tn < 4; ++tn) nvj[tn] = nv[bj * 128 + wn + tn * 16 + cc];
  float s = 0.f;
#pragma unroll
  for (int tm = 0; tm < 4; ++tm) {
#pragma unroll
    for (int e = 0; e < 4; ++e) {
      const int il = wm + tm * 16 + cr + e;
      const float cai = ca_l[il], cbi = cb_l[il];
#pragma unroll
      for (int tn = 0; tn < 4; ++tn) {
        const float dap = sqrtf(fmaxf(fmaf(-2.f, accP[tm][tn][e], nvj[tn] + cai), 1e-12f));
        const float dan = sqrtf(fmaxf(fmaf(-2.f, accN[tm][tn][e], nvj[tn] + cbi), 1e-12f));
        s += fmaxf(dap - dan + MARGINV, 0.f);
      }
    }
  }
  for (int off = 32; off; off >>= 1) s += __shfl_xor(s, off);
  const int lane = t & 63;
  if (lane == 0) ps[w] = s;
  __syncthreads();
  if (t == 0) partial[blockIdx.x] = (ps[0] + ps[1]) + (ps[2] + ps[3]);
}

// ---------------- Kernel 3: finalize (1 block, 1024 partials) ----------------
__global__ __launch_bounds__(256) void finalize_kernel(const float* __restrict__ partial,
                                                       float* __restrict__ out) {
  const int t = threadIdx.x;
  const float4* P4 = (const float4*)partial;  // 1024 floats = 256 float4
  float4 v = P4[t];
  float s = (v.x + v.y) + (v.z + v.w);
  for (int off = 32; off; off >>= 1) s += __shfl_xor(s, off);
  __shared__ float ps[4];
  const int w = t >> 6, lane = t & 63;
  if (lane == 0) ps[w] = s;
  __syncthreads();
  if (t == 0)
    out[0] = ((ps[0] + ps[1]) + (ps[2] + ps[3])) * (1.0f / ((float)BSZ * (float)BSZ));
}

// ---------------- Launch ----------------
extern "C" void kernel_launch(void* const* d_in, const int* in_sizes, int n_in,
                              void* d_out, int out_size, void* d_ws, size_t ws_size,
                              hipStream_t stream) {
  const float* feat = (const float*)d_in[0];
  const int* labels = (const int*)d_in[1];
  float* out = (float*)d_out;

  char* ws = (char*)d_ws;
  uint8_t* Fq      = (uint8_t*)ws;                                // 4 MB
  float* norm2     = (float*)(ws + (size_t)4194304);              // 16 KB
  float* sums      = (float*)(ws + (size_t)4194304 + 16384);      // 16 KB
  float* nv        = (float*)(ws + (size_t)4194304 + 32768);      // 16 KB
  int* pos_idx     = (int*)  (ws + (size_t)4194304 + 49152);      // 16 KB
  int* neg_idx     = (int*)  (ws + (size_t)4194304 + 65536);      // 16 KB
  float* partial   = (float*)(ws + (size_t)4194304 + 81920);      // 4 KB

  // JAX partitionable split: k_i = threefry(base_key=(0,42), (0, i))
  uint32_t k1a, k1b, k2a, k2b;
  threefry2x32(0u, 42u, 0u, 0u, k1a, k1b);  // k1 -> pos uniforms
  threefry2x32(0u, 42u, 0u, 1u, k2a, k2b);  // k2 -> neg uniforms

  prep_sample_kernel<<<dim3(PS_BLOCKS), dim3(256), 0, stream>>>(
      feat, Fq, norm2, sums, nv, labels, pos_idx, neg_idx, k1a, k1b, k2a, k2b);
  gemmloss_kernel<<<dim3(GL_BLOCKS), dim3(256), 0, stream>>>(
      Fq, norm2, sums, nv, pos_idx, neg_idx, partial);
  finalize_kernel<<<dim3(1), dim3(256), 0, stream>>>(partial, out);
}